// Round 1
// baseline (29.240 us; speedup 1.0000x reference)
//
#include <hip/hip_runtime.h>
#include <math.h>

#define BB   16
#define VV   8
#define HW_  65536            // 256*256
#define HWQ  16384            // HW_/4
#define NQUAD (BB * HWQ)      // 262144 quads (4 pixels each)
#define NBLK 1024
#define NTHR 256
#define NPIX_F 3145728.0f     // B*3*H*W (mean denominator)

// access j-th float of a float4 (static j under full unroll)
#define F4(a, j) (((const float*)&(a))[j])

__global__ __launch_bounds__(NTHR) void pvs_main(
    const float* __restrict__ y0,
    const float* __restrict__ ycond,
    const float* __restrict__ angle,
    const float* __restrict__ noise,
    const float* __restrict__ rand_u,
    const float* __restrict__ Wk,
    const float* __restrict__ bk,
    const float* __restrict__ gammas,
    const int*   __restrict__ view_count,
    const int*   __restrict__ tt,
    float* __restrict__ partials)
{
    __shared__ float s_sq[BB], s_sq1[BB], s_mod[BB];
    __shared__ int   s_vc[BB];
    __shared__ float s_red[NTHR];

    if (threadIdx.x < BB) {
        int b = threadIdx.x;
        int t = tt[b];
        float g1 = gammas[t - 1];
        float g2 = gammas[t];
        float sg = (g2 - g1) * rand_u[b] + g1;
        s_sq[b]  = sqrtf(sg);
        s_sq1[b] = sqrtf(1.0f - sg);
        s_mod[b] = 0.1f * (sg + angle[b]);
        s_vc[b]  = view_count[b];
    }
    __syncthreads();

    // Wk (4,6) row-major, bk (4) — uniform, L1-resident
    float wk[4][6], bkr[4];
    #pragma unroll
    for (int o = 0; o < 4; ++o) {
        bkr[o] = bk[o];
        #pragma unroll
        for (int c = 0; c < 6; ++c) wk[o][c] = Wk[o * 6 + c];
    }

    float acc = 0.0f;
    for (int q = blockIdx.x * NTHR + threadIdx.x; q < NQUAD; q += NBLK * NTHR) {
        int b  = q >> 14;              // q / HWQ
        int hw = (q & (HWQ - 1)) << 2; // 4-pixel base within plane
        float sq = s_sq[b], sq1 = s_sq1[b], md = s_mod[b];
        int vc = s_vc[b];

        float4 y0v[3], nzv[3];
        #pragma unroll
        for (int c = 0; c < 3; ++c) {
            y0v[c] = *(const float4*)(y0    + (b * 3 + c) * HW_ + hw);
            nzv[c] = *(const float4*)(noise + (b * 3 + c) * HW_ + hw);
        }
        float4 ycv[VV][3];
        #pragma unroll
        for (int v = 0; v < VV; ++v) {
            #pragma unroll
            for (int c = 0; c < 3; ++c) {
                ycv[v][c] = *(const float4*)(ycond + ((b * VV + v) * 3 + c) * HW_ + hw);
            }
        }

        #pragma unroll
        for (int j = 0; j < 4; ++j) {
            // y_noisy for this pixel
            float yn0 = fmaf(sq, F4(y0v[0], j), sq1 * F4(nzv[0], j));
            float yn1 = fmaf(sq, F4(y0v[1], j), sq1 * F4(nzv[1], j));
            float yn2 = fmaf(sq, F4(y0v[2], j), sq1 * F4(nzv[2], j));

            // v-independent part of the 4x6 linear layer (channels 3..5 + bias + 0.1*mod)
            float base[4];
            #pragma unroll
            for (int o = 0; o < 4; ++o) {
                base[o] = fmaf(wk[o][3], yn0,
                          fmaf(wk[o][4], yn1,
                          fmaf(wk[o][5], yn2, bkr[o] + md)));
            }

            float outv[VV][4];
            float m = -3.4e38f;
            #pragma unroll
            for (int v = 0; v < VV; ++v) {
                float x0 = F4(ycv[v][0], j);
                float x1 = F4(ycv[v][1], j);
                float x2 = F4(ycv[v][2], j);
                #pragma unroll
                for (int o = 0; o < 4; ++o) {
                    outv[v][o] = fmaf(wk[o][0], x0,
                                 fmaf(wk[o][1], x1,
                                 fmaf(wk[o][2], x2, base[o])));
                }
                if (v < vc) m = fmaxf(m, outv[v][3]);
            }

            float S = 0.0f, nh0 = 0.0f, nh1 = 0.0f, nh2 = 0.0f;
            #pragma unroll
            for (int v = 0; v < VV; ++v) {
                float w = (v < vc) ? __expf(outv[v][3] - m) : 0.0f;
                S   += w;
                nh0  = fmaf(outv[v][0], w, nh0);
                nh1  = fmaf(outv[v][1], w, nh1);
                nh2  = fmaf(outv[v][2], w, nh2);
            }
            float invS = 1.0f / S;
            float d0 = F4(nzv[0], j) - nh0 * invS;
            float d1 = F4(nzv[1], j) - nh1 * invS;
            float d2 = F4(nzv[2], j) - nh2 * invS;
            acc = fmaf(d0, d0, fmaf(d1, d1, fmaf(d2, d2, acc)));
        }
    }

    // deterministic block reduction
    s_red[threadIdx.x] = acc;
    __syncthreads();
    #pragma unroll
    for (int s = NTHR / 2; s > 0; s >>= 1) {
        if (threadIdx.x < s) s_red[threadIdx.x] += s_red[threadIdx.x + s];
        __syncthreads();
    }
    if (threadIdx.x == 0) partials[blockIdx.x] = s_red[0];
}

__global__ __launch_bounds__(256) void pvs_reduce(const float* __restrict__ partials,
                                                 float* __restrict__ out)
{
    __shared__ double s[256];
    double a = 0.0;
    for (int i = threadIdx.x; i < NBLK; i += 256) a += (double)partials[i];
    s[threadIdx.x] = a;
    __syncthreads();
    #pragma unroll
    for (int st = 128; st > 0; st >>= 1) {
        if (threadIdx.x < st) s[threadIdx.x] += s[threadIdx.x + st];
        __syncthreads();
    }
    if (threadIdx.x == 0) out[0] = (float)(s[0] / (double)NPIX_F);
}

extern "C" void kernel_launch(void* const* d_in, const int* in_sizes, int n_in,
                              void* d_out, int out_size, void* d_ws, size_t ws_size,
                              hipStream_t stream) {
    const float* y0      = (const float*)d_in[0];
    const float* ycond   = (const float*)d_in[1];
    const float* angle   = (const float*)d_in[2];
    const float* noise   = (const float*)d_in[3];
    const float* rand_u  = (const float*)d_in[4];
    const float* Wk      = (const float*)d_in[5];
    const float* bk      = (const float*)d_in[6];
    const float* gammas  = (const float*)d_in[7];
    const int*   vc      = (const int*)d_in[8];
    const int*   tt      = (const int*)d_in[9];
    float* partials = (float*)d_ws;
    float* out      = (float*)d_out;

    pvs_main<<<NBLK, NTHR, 0, stream>>>(y0, ycond, angle, noise, rand_u,
                                        Wk, bk, gammas, vc, tt, partials);
    pvs_reduce<<<1, 256, 0, stream>>>(partials, out);
}